// Round 1
// baseline (808.783 us; speedup 1.0000x reference)
//
#include <hip/hip_runtime.h>
#include <math.h>

#define N_NODES 20000
#define E_EDGES 320000
#define F_DIM   960
#define S_DIM   256

__device__ __forceinline__ float siluf(float x) {
    return x / (1.0f + expf(-x));
}

__device__ __forceinline__ float lane_bcast(float x, int l) {
    return __int_as_float(__builtin_amdgcn_readlane(__float_as_int(x), l));
}

// ---------------------------------------------------------------------------
// K0a: fold weights.
//   Bcat[k][j] (256 x 1024): j<256 -> Wu = W_sc@W1a ; 256..511 -> Wv = W_sc@W1b
//                            512..767 -> W_ai1 copy ; 768..1023 -> W_ci1 copy
//   We[p][j]  (32 x 256):  W_ed @ W1c
//   c0[j]:  b_sc@(W1a+W1b) + b_ed@W1c + b_b1
// ---------------------------------------------------------------------------
__global__ void prep_kernel(const float* __restrict__ W_sc, const float* __restrict__ W_ed,
                            const float* __restrict__ W_b1, const float* __restrict__ b_sc,
                            const float* __restrict__ b_ed, const float* __restrict__ b_b1,
                            const float* __restrict__ W_ai1, const float* __restrict__ W_ci1,
                            float* __restrict__ Bcat, float* __restrict__ We, float* __restrict__ c0)
{
    int idx = blockIdx.x * 256 + threadIdx.x;
    if (idx < 256 * 1024) {
        int k = idx >> 10, j = idx & 1023;
        float s = 0.0f;
        if (j < 256) {
            for (int m = 0; m < 256; ++m) s += W_sc[k * 256 + m] * W_b1[m * 256 + j];
        } else if (j < 512) {
            int jj = j - 256;
            for (int m = 0; m < 256; ++m) s += W_sc[k * 256 + m] * W_b1[(256 + m) * 256 + jj];
        } else if (j < 768) {
            s = W_ai1[k * 256 + (j - 512)];
        } else {
            s = W_ci1[k * 256 + (j - 768)];
        }
        Bcat[idx] = s;
    } else if (idx < 256 * 1024 + 32 * 256) {
        int t = idx - 256 * 1024;
        int p = t >> 8, j = t & 255;
        float s = 0.0f;
        for (int m = 0; m < 256; ++m) s += W_ed[p * 256 + m] * W_b1[(512 + m) * 256 + j];
        We[t] = s;
    } else if (idx < 256 * 1024 + 32 * 256 + 256) {
        int j = idx - 256 * 1024 - 32 * 256;
        float s = b_b1[j];
        for (int m = 0; m < 256; ++m) {
            s += b_sc[m] * (W_b1[m * 256 + j] + W_b1[(256 + m) * 256 + j]);
            s += b_ed[m] * W_b1[(512 + m) * 256 + j];
        }
        c0[j] = s;
    }
}

// K0b: zero-init atomic accumulators (ws is re-poisoned to 0xAA every launch).
__global__ void init_kernel(unsigned* __restrict__ bmax_keys, float* __restrict__ contrib)
{
    int i = blockIdx.x * 256 + threadIdx.x;
    if (i < N_NODES) {
        bmax_keys[i] = 0u;  // encodes "-inf" in monotone float->uint key space
        #pragma unroll
        for (int q = 0; q < 8; ++q) contrib[i * 8 + q] = 0.0f;
    }
}

// ---------------------------------------------------------------------------
// K1: fused node GEMM. scal(N x 256) @ Bcat(256 x 1024) with epilogues:
//   g=0 -> u (+c0), g=1 -> v, g=2 -> silu->dot(W_ai2)->exp = ai,
//   g=3 -> silu->dot(W_ci2)->exp + 1e-7 = bsum init (ci + eps)
// ---------------------------------------------------------------------------
__global__ __launch_bounds__(256) void node_kernel(
    const float* __restrict__ nf, const float* __restrict__ Bcat, const float* __restrict__ c0,
    const float* __restrict__ b_ai1, const float* __restrict__ W_ai2, const float* __restrict__ b_ai2,
    const float* __restrict__ b_ci1, const float* __restrict__ W_ci2, const float* __restrict__ b_ci2,
    float* __restrict__ u, float* __restrict__ v, float* __restrict__ bsum, float* __restrict__ out_ai)
{
    __shared__ float at[16][256];
    const int tid = threadIdx.x;
    const int node0 = blockIdx.x * 16;

    for (int idx = tid; idx < 16 * 256; idx += 256) {
        int n = idx >> 8, k = idx & 255;
        at[n][k] = nf[(node0 + n) * F_DIM + k];
    }
    __syncthreads();

    float acc[16][4];
    #pragma unroll
    for (int n = 0; n < 16; ++n)
        #pragma unroll
        for (int g = 0; g < 4; ++g) acc[n][g] = 0.0f;

    for (int k = 0; k < 256; k += 4) {
        float b[4][4];
        #pragma unroll
        for (int kk = 0; kk < 4; ++kk)
            #pragma unroll
            for (int g = 0; g < 4; ++g)
                b[kk][g] = Bcat[(k + kk) * 1024 + g * 256 + tid];
        #pragma unroll
        for (int n = 0; n < 16; ++n) {
            float4 a4 = *(const float4*)&at[n][k];
            #pragma unroll
            for (int g = 0; g < 4; ++g)
                acc[n][g] += a4.x * b[0][g] + a4.y * b[1][g] + a4.z * b[2][g] + a4.w * b[3][g];
        }
    }

    float c0v = c0[tid];
    #pragma unroll
    for (int n = 0; n < 16; ++n) {
        u[(node0 + n) * 256 + tid] = acc[n][0] + c0v;
        v[(node0 + n) * 256 + tid] = acc[n][1];
    }

    const int wid = tid >> 6, lane = tid & 63;

    // ai epilogue
    float bai1v = b_ai1[tid], wai2v = W_ai2[tid], bai2 = b_ai2[0];
    __syncthreads();
    #pragma unroll
    for (int n = 0; n < 16; ++n)
        at[n][tid] = siluf(acc[n][2] + bai1v) * wai2v;
    __syncthreads();
    #pragma unroll
    for (int q = 0; q < 4; ++q) {
        int n = wid * 4 + q;
        float s = at[n][lane] + at[n][lane + 64] + at[n][lane + 128] + at[n][lane + 192];
        #pragma unroll
        for (int off = 32; off > 0; off >>= 1) s += __shfl_down(s, off);
        if (lane == 0) out_ai[node0 + n] = expf(s + bai2);
    }

    // ci epilogue -> bsum seed (ci + 1e-7)
    float bci1v = b_ci1[tid], wci2v = W_ci2[tid], bci2 = b_ci2[0];
    __syncthreads();
    #pragma unroll
    for (int n = 0; n < 16; ++n)
        at[n][tid] = siluf(acc[n][3] + bci1v) * wci2v;
    __syncthreads();
    #pragma unroll
    for (int q = 0; q < 4; ++q) {
        int n = wid * 4 + q;
        float s = at[n][lane] + at[n][lane + 64] + at[n][lane + 128] + at[n][lane + 192];
        #pragma unroll
        for (int off = 32; off > 0; off >>= 1) s += __shfl_down(s, off);
        if (lane == 0) bsum[node0 + n] = expf(s + bci2) + 1e-7f;
    }
}

// ---------------------------------------------------------------------------
// K2: per-edge (one wave per edge): RBF -> emb@We (We in VGPRs, emb via
// readlane broadcast) + u[src] + v[dst] -> silu -> dot(W_b2) -> bij.
// Stores bij, rhat; atomicMax of monotone-encoded bij into bmax_keys[dst].
// ---------------------------------------------------------------------------
__global__ __launch_bounds__(256, 2) void edge1_kernel(
    const int* __restrict__ ei, const float* __restrict__ pos,
    const float* __restrict__ u, const float* __restrict__ v,
    const float* __restrict__ We, const float* __restrict__ W_b2, const float* __restrict__ b_b2,
    float* __restrict__ bij, float* __restrict__ rxA, float* __restrict__ ryA, float* __restrict__ rzA,
    unsigned* __restrict__ bmax_keys)
{
    const int lane = threadIdx.x & 63;
    const int wv = blockIdx.x * 4 + (threadIdx.x >> 6);
    const int stride = gridDim.x << 2;

    float4 we[32];
    #pragma unroll
    for (int k = 0; k < 32; ++k) we[k] = *(const float4*)&We[k * 256 + lane * 4];
    float4 w2 = *(const float4*)&W_b2[lane * 4];
    float bb2 = b_b2[0];

    const float start = 0.006737946999085467f;           // exp(-5)
    const float mustep = (1.0f - start) / 31.0f;
    const float bx = (2.0f / 32.0f) * (1.0f - start);
    const float beta = 1.0f / (bx * bx);
    const int kk = lane & 31;
    const float mu = start + (float)kk * mustep;
    const float PI_F = 3.14159265358979323846f;

    for (int e = wv; e < E_EDGES; e += stride) {
        int s = ei[e], d = ei[E_EDGES + e];
        float px = pos[3 * d + 0] - pos[3 * s + 0];
        float py = pos[3 * d + 1] - pos[3 * s + 1];
        float pz = pos[3 * d + 2] - pos[3 * s + 2];
        float nrm = sqrtf(px * px + py * py + pz * pz);
        float inv = 1.0f / (nrm + 1e-8f);
        float rx = px * inv, ry = py * inv, rz = pz * inv;
        float cc = (nrm < 5.0f) ? 0.5f * (cosf(PI_F * nrm * 0.2f) + 1.0f) : 0.0f;
        float t = expf(-nrm);
        float dm = t - mu;
        float em = cc * expf(-beta * dm * dm);   // lane kk's RBF value

        float4 uv = *(const float4*)&u[s * 256 + lane * 4];
        float4 vv = *(const float4*)&v[d * 256 + lane * 4];
        float h0 = uv.x + vv.x, h1 = uv.y + vv.y, h2 = uv.z + vv.z, h3 = uv.w + vv.w;

        #pragma unroll
        for (int k = 0; k < 32; ++k) {
            float ek = lane_bcast(em, k);
            h0 += ek * we[k].x;
            h1 += ek * we[k].y;
            h2 += ek * we[k].z;
            h3 += ek * we[k].w;
        }

        float p = siluf(h0) * w2.x + siluf(h1) * w2.y + siluf(h2) * w2.z + siluf(h3) * w2.w;
        #pragma unroll
        for (int off = 32; off > 0; off >>= 1) p += __shfl_down(p, off);

        if (lane == 0) {
            float bv = p + bb2;
            bij[e] = bv;
            rxA[e] = rx; ryA[e] = ry; rzA[e] = rz;
            unsigned bu = __float_as_uint(bv);
            unsigned key = (bu & 0x80000000u) ? ~bu : (bu | 0x80000000u);
            atomicMax(&bmax_keys[d], key);
        }
    }
}

// K3: e = exp(bij - bmax[dst]); segsum into bsum (seeded with ci+1e-7).
__global__ void edge2_kernel(const int* __restrict__ ei, const float* __restrict__ bij,
                             const unsigned* __restrict__ bmax_keys,
                             float* __restrict__ earr, float* __restrict__ bsum)
{
    int i = blockIdx.x * 256 + threadIdx.x;
    if (i >= E_EDGES) return;
    int d = ei[E_EDGES + i];
    unsigned key = bmax_keys[d];
    float m = (key & 0x80000000u) ? __uint_as_float(key & 0x7FFFFFFFu) : __uint_as_float(~key);
    float ev = expf(bij[i] - m);
    earr[i] = ev;
    atomicAdd(&bsum[d], ev);
}

// K4: gamma = e/bsum[dst]; scatter gamma*outer(rhat) (6 sym comps) + gamma.
__global__ void edge3_kernel(const int* __restrict__ ei, const float* __restrict__ earr,
                             const float* __restrict__ bsum,
                             const float* __restrict__ rxA, const float* __restrict__ ryA,
                             const float* __restrict__ rzA, float* __restrict__ contrib)
{
    int i = blockIdx.x * 256 + threadIdx.x;
    if (i >= E_EDGES) return;
    int d = ei[E_EDGES + i];
    float gamma = earr[i] / bsum[d];
    float rx = rxA[i], ry = ryA[i], rz = rzA[i];
    float* c = &contrib[d * 8];
    atomicAdd(c + 0, gamma * rx * rx);
    atomicAdd(c + 1, gamma * ry * ry);
    atomicAdd(c + 2, gamma * rz * rz);
    atomicAdd(c + 3, gamma * rx * ry);
    atomicAdd(c + 4, gamma * rx * rz);
    atomicAdd(c + 5, gamma * ry * rz);
    atomicAdd(c + 6, gamma);
}

// K5: sigma = ai*I - ai*sum(gamma*outer) + 1e-6*I ; emit sigma + sum_gamma.
__global__ void final_kernel(const float* __restrict__ contrib, const float* __restrict__ out_ai,
                             float* __restrict__ out_sigma, float* __restrict__ out_sg)
{
    int i = blockIdx.x * 256 + threadIdx.x;
    if (i >= N_NODES) return;
    float ai = out_ai[i];
    const float* c = &contrib[i * 8];
    float* s = &out_sigma[i * 9];
    float d0 = ai + 1e-6f;
    s[0] = d0 - ai * c[0];
    s[1] = -ai * c[3];
    s[2] = -ai * c[4];
    s[3] = -ai * c[3];
    s[4] = d0 - ai * c[1];
    s[5] = -ai * c[5];
    s[6] = -ai * c[4];
    s[7] = -ai * c[5];
    s[8] = d0 - ai * c[2];
    out_sg[i] = c[6];
}

extern "C" void kernel_launch(void* const* d_in, const int* in_sizes, int n_in,
                              void* d_out, int out_size, void* d_ws, size_t ws_size,
                              hipStream_t stream)
{
    const float* nf    = (const float*)d_in[0];
    const float* pos   = (const float*)d_in[1];
    const int*   ei    = (const int*)  d_in[2];
    const float* W_ai1 = (const float*)d_in[3];
    const float* b_ai1 = (const float*)d_in[4];
    const float* W_ai2 = (const float*)d_in[5];
    const float* b_ai2 = (const float*)d_in[6];
    const float* W_ci1 = (const float*)d_in[7];
    const float* b_ci1 = (const float*)d_in[8];
    const float* W_ci2 = (const float*)d_in[9];
    const float* b_ci2 = (const float*)d_in[10];
    const float* W_sc  = (const float*)d_in[11];
    const float* b_sc  = (const float*)d_in[12];
    const float* W_ed  = (const float*)d_in[13];
    const float* b_ed  = (const float*)d_in[14];
    const float* W_b1  = (const float*)d_in[15];
    const float* b_b1  = (const float*)d_in[16];
    const float* W_b2  = (const float*)d_in[17];
    const float* b_b2  = (const float*)d_in[18];

    float* ws = (float*)d_ws;
    float*    Bcat    = ws;                        // 262144
    float*    We      = Bcat + 262144;             // 8192
    float*    c0      = We + 8192;                 // 256
    float*    u       = c0 + 256;                  // N*256
    float*    v       = u + N_NODES * 256;         // N*256
    float*    bsum    = v + N_NODES * 256;         // N
    unsigned* bmax    = (unsigned*)(bsum + N_NODES); // N
    float*    contrib = (float*)(bmax + N_NODES);  // N*8
    float*    bijA    = contrib + N_NODES * 8;     // E
    float*    earr    = bijA + E_EDGES;            // E
    float*    rxA     = earr + E_EDGES;            // E
    float*    ryA     = rxA + E_EDGES;             // E
    float*    rzA     = ryA + E_EDGES;             // E

    float* out       = (float*)d_out;
    float* out_sigma = out;                  // N*9
    float* out_ai    = out + N_NODES * 9;    // N
    float* out_sg    = out + N_NODES * 10;   // N

    prep_kernel<<<1058, 256, 0, stream>>>(W_sc, W_ed, W_b1, b_sc, b_ed, b_b1, W_ai1, W_ci1,
                                          Bcat, We, c0);
    init_kernel<<<79, 256, 0, stream>>>(bmax, contrib);
    node_kernel<<<1250, 256, 0, stream>>>(nf, Bcat, c0, b_ai1, W_ai2, b_ai2,
                                          b_ci1, W_ci2, b_ci2, u, v, bsum, out_ai);
    edge1_kernel<<<512, 256, 0, stream>>>(ei, pos, u, v, We, W_b2, b_b2,
                                          bijA, rxA, ryA, rzA, bmax);
    edge2_kernel<<<1250, 256, 0, stream>>>(ei, bijA, bmax, earr, bsum);
    edge3_kernel<<<1250, 256, 0, stream>>>(ei, earr, bsum, rxA, ryA, rzA, contrib);
    final_kernel<<<79, 256, 0, stream>>>(contrib, out_ai, out_sigma, out_sg);
}